// Round 10
// baseline (538.000 us; speedup 1.0000x reference)
//
#include <hip/hip_runtime.h>
#include <math.h>

// ---------------------------------------------------------------------------
// VisionMambaDenoiser. Round 10: R9 structure (LDS stride 40 + bf16-only u)
// with corrected workspace layout. R8/R9 failures were buffer undersizing:
// 8192x384 bf16 = 1,572,864 floats (I had 393,216), causing u16/bc/Pc and
// seqo_b/W2b overlaps. All regions re-audited pairwise for liveness overlap.
// ---------------------------------------------------------------------------

typedef short bf16x8 __attribute__((ext_vector_type(8)));
typedef float f32x4 __attribute__((ext_vector_type(4)));

__device__ inline unsigned short f2bf(float f) {
    unsigned int u = __float_as_uint(f);
    unsigned int r = (u + 0x7fff + ((u >> 16) & 1)) >> 16;   // RNE
    return (unsigned short)r;
}
__device__ inline float bf2f(unsigned short s) {
    return __uint_as_float(((unsigned int)s) << 16);
}

// ---------------- flexible bf16 MFMA GEMM: C = A @ W^T (+bias) --------------
__global__ __launch_bounds__(256) void gemm_mfma_flex(
    const unsigned short* __restrict__ A, const unsigned short* __restrict__ W,
    void* __restrict__ Cout, const float* __restrict__ bias,
    int M, int N, int K, int out_bf16)
{
    __shared__ unsigned short As[128][40];   // stride 40: <=2-way banks (free)
    __shared__ unsigned short Bs[128][40];
    const int tid = threadIdx.x;
    const int wave = tid >> 6, lane = tid & 63;
    const int wm = (wave & 1) * 64, wn = (wave >> 1) * 64;
    const int m0 = blockIdx.y * 128, n0 = blockIdx.x * 128;
    const int quad = lane >> 4, lr = lane & 15;
    const uint4 z4 = {0, 0, 0, 0};

    f32x4 acc[4][4];
    #pragma unroll
    for (int i = 0; i < 4; ++i)
        #pragma unroll
        for (int j = 0; j < 4; ++j)
            acc[i][j] = (f32x4){0.f, 0.f, 0.f, 0.f};

    const int r = tid >> 2, kq = tid & 3;
    for (int k0 = 0; k0 < K; k0 += 32) {
        #pragma unroll
        for (int half = 0; half < 2; ++half) {
            int rr = r + half * 64;
            *(uint4*)(&As[rr][kq * 8]) =
                *(const uint4*)(A + (size_t)(m0 + rr) * K + k0 + kq * 8);
            uint4 bv = z4;
            if (n0 + rr < N)
                bv = *(const uint4*)(W + (size_t)(n0 + rr) * K + k0 + kq * 8);
            *(uint4*)(&Bs[rr][kq * 8]) = bv;
        }
        __syncthreads();
        bf16x8 af[4], bfr[4];
        #pragma unroll
        for (int i = 0; i < 4; ++i) af[i] = *(const bf16x8*)(&As[wm + i * 16 + lr][quad * 8]);
        #pragma unroll
        for (int j = 0; j < 4; ++j) bfr[j] = *(const bf16x8*)(&Bs[wn + j * 16 + lr][quad * 8]);
        #pragma unroll
        for (int i = 0; i < 4; ++i)
            #pragma unroll
            for (int j = 0; j < 4; ++j)
                acc[i][j] = __builtin_amdgcn_mfma_f32_16x16x32_bf16(af[i], bfr[j], acc[i][j], 0, 0, 0);
        __syncthreads();
    }

    #pragma unroll
    for (int i = 0; i < 4; ++i) {
        int gm = m0 + wm + i * 16 + quad * 4;
        #pragma unroll
        for (int j = 0; j < 4; ++j) {
            int gn = n0 + wn + j * 16 + lr;
            if (gn >= N) continue;
            float bv = bias ? bias[gn] : 0.f;
            #pragma unroll
            for (int rr = 0; rr < 4; ++rr) {
                float v = acc[i][j][rr] + bv;
                if (out_bf16) ((unsigned short*)Cout)[(size_t)(gm + rr) * N + gn] = f2bf(v);
                else          ((float*)Cout)[(size_t)(gm + rr) * N + gn] = v;
            }
        }
    }
}

// ---------------- combined x_proj+dt_proj GEMM (N=416, K=384) ---------------
__global__ __launch_bounds__(256) void gemm_xd(
    const unsigned short* __restrict__ A, const unsigned short* __restrict__ W,
    float* __restrict__ delta, float* __restrict__ bc,
    const float* __restrict__ dtb)
{
    __shared__ unsigned short As[128][40];
    __shared__ unsigned short Bs[128][40];
    const int N = 416, K = 384;
    const int tid = threadIdx.x;
    const int wave = tid >> 6, lane = tid & 63;
    const int wm = (wave & 1) * 64, wn = (wave >> 1) * 64;
    const int m0 = blockIdx.y * 128, n0 = blockIdx.x * 128;
    const int quad = lane >> 4, lr = lane & 15;
    const uint4 z4 = {0, 0, 0, 0};

    f32x4 acc[4][4];
    #pragma unroll
    for (int i = 0; i < 4; ++i)
        #pragma unroll
        for (int j = 0; j < 4; ++j)
            acc[i][j] = (f32x4){0.f, 0.f, 0.f, 0.f};

    const int r = tid >> 2, kq = tid & 3;
    for (int k0 = 0; k0 < K; k0 += 32) {
        #pragma unroll
        for (int half = 0; half < 2; ++half) {
            int rr = r + half * 64;
            *(uint4*)(&As[rr][kq * 8]) =
                *(const uint4*)(A + (size_t)(m0 + rr) * K + k0 + kq * 8);
            uint4 bv = z4;
            if (n0 + rr < N)
                bv = *(const uint4*)(W + (size_t)(n0 + rr) * K + k0 + kq * 8);
            *(uint4*)(&Bs[rr][kq * 8]) = bv;
        }
        __syncthreads();
        bf16x8 af[4], bfr[4];
        #pragma unroll
        for (int i = 0; i < 4; ++i) af[i] = *(const bf16x8*)(&As[wm + i * 16 + lr][quad * 8]);
        #pragma unroll
        for (int j = 0; j < 4; ++j) bfr[j] = *(const bf16x8*)(&Bs[wn + j * 16 + lr][quad * 8]);
        #pragma unroll
        for (int i = 0; i < 4; ++i)
            #pragma unroll
            for (int j = 0; j < 4; ++j)
                acc[i][j] = __builtin_amdgcn_mfma_f32_16x16x32_bf16(af[i], bfr[j], acc[i][j], 0, 0, 0);
        __syncthreads();
    }

    #pragma unroll
    for (int i = 0; i < 4; ++i) {
        int gm = m0 + wm + i * 16 + quad * 4;
        #pragma unroll
        for (int j = 0; j < 4; ++j) {
            int gn = n0 + wn + j * 16 + lr;
            if (gn >= N) continue;
            #pragma unroll
            for (int rr = 0; rr < 4; ++rr) {
                float v = acc[i][j][rr];
                if (gn < 384) {
                    v += dtb[gn];
                    v = (v > 20.f) ? v : log1pf(__expf(v));
                    delta[(size_t)(gm + rr) * 384 + gn] = v;
                } else {
                    bc[(size_t)(gm + rr) * 32 + gn - 384] = v;
                }
            }
        }
    }
}

// ---------------- decoder MFMA GEMM (4 batches): Db=bf16(relu(A@W^T+b)) -----
__global__ __launch_bounds__(256) void gemm_mfma_relu_bf16(
    const unsigned short* __restrict__ A0, const unsigned short* __restrict__ W,
    unsigned short* __restrict__ C0, const float* __restrict__ bias, int base_b)
{
    __shared__ unsigned short smem[10240];       // As|Bs (2x128x40), reused as Ct
    unsigned short* As = smem;
    unsigned short* Bs = smem + 5120;
    const int N = 16384, K = 192;
    const int tid = threadIdx.x;
    const int wave = tid >> 6, lane = tid & 63;
    const int wm = (wave & 1) * 64, wn = (wave >> 1) * 64;
    const int m0 = blockIdx.y * 128, n0 = blockIdx.x * 128;
    const int z = blockIdx.z;
    const unsigned short* A = A0 + (size_t)(base_b + z) * 1024 * 192;
    unsigned short* C = C0 + (size_t)z * 16777216;
    const int quad = lane >> 4, lr = lane & 15;

    f32x4 acc[4][4];
    #pragma unroll
    for (int i = 0; i < 4; ++i)
        #pragma unroll
        for (int j = 0; j < 4; ++j)
            acc[i][j] = (f32x4){0.f, 0.f, 0.f, 0.f};

    const int r = tid >> 2, kq = tid & 3;
    for (int k0 = 0; k0 < K; k0 += 32) {
        #pragma unroll
        for (int half = 0; half < 2; ++half) {
            int rr = r + half * 64;
            *(uint4*)(&As[rr * 40 + kq * 8]) =
                *(const uint4*)(A + (size_t)(m0 + rr) * K + k0 + kq * 8);
            *(uint4*)(&Bs[rr * 40 + kq * 8]) =
                *(const uint4*)(W + (size_t)(n0 + rr) * K + k0 + kq * 8);
        }
        __syncthreads();
        bf16x8 af[4], bfr[4];
        #pragma unroll
        for (int i = 0; i < 4; ++i) af[i] = *(const bf16x8*)(&As[(wm + i * 16 + lr) * 40 + quad * 8]);
        #pragma unroll
        for (int j = 0; j < 4; ++j) bfr[j] = *(const bf16x8*)(&Bs[(wn + j * 16 + lr) * 40 + quad * 8]);
        #pragma unroll
        for (int i = 0; i < 4; ++i)
            #pragma unroll
            for (int j = 0; j < 4; ++j)
                acc[i][j] = __builtin_amdgcn_mfma_f32_16x16x32_bf16(af[i], bfr[j], acc[i][j], 0, 0, 0);
        __syncthreads();
    }

    unsigned short* Ct = smem;                   // 64*136 = 8704 <= 10240
    #pragma unroll
    for (int h = 0; h < 2; ++h) {
        if ((wave & 1) == h) {
            #pragma unroll
            for (int i = 0; i < 4; ++i) {
                int lrow = i * 16 + quad * 4;
                #pragma unroll
                for (int j = 0; j < 4; ++j) {
                    int lcol = wn + j * 16 + lr;
                    float bv = bias[(n0 + lcol) & 63];
                    #pragma unroll
                    for (int rr = 0; rr < 4; ++rr) {
                        float v = fmaxf(acc[i][j][rr] + bv, 0.f);
                        Ct[(lrow + rr) * 136 + lcol] = f2bf(v);
                    }
                }
            }
        }
        __syncthreads();
        #pragma unroll
        for (int p = 0; p < 4; ++p) {
            int idx = p * 256 + tid;
            int row = idx >> 4, cg = idx & 15;
            *(uint4*)(C + (size_t)(m0 + h * 64 + row) * N + n0 + cg * 8) =
                *(const uint4*)(&Ct[row * 136 + cg * 8]);
        }
        __syncthreads();
    }
}

// ---------------- fused prep: im2col + all weight transforms ----------------
__global__ __launch_bounds__(256) void prep_all(
    const float* __restrict__ x, unsigned short* __restrict__ P,
    const float* __restrict__ patch_w, unsigned short* __restrict__ wp,
    const float* __restrict__ in_proj_w, unsigned short* __restrict__ wi,
    const float* __restrict__ out_proj_w, unsigned short* __restrict__ wo,
    const float* __restrict__ deconv_w, unsigned short* __restrict__ W2,
    const float* __restrict__ dec_conv_w, unsigned short* __restrict__ wconv,
    const float* __restrict__ dtw, const float* __restrict__ xpw,
    unsigned short* __restrict__ wxd)
{
    int i = blockIdx.x * 256 + threadIdx.x;     // 9974784 total
    if (i < 6291456) {
        int col = i % 768, row = i / 768;
        int b = row >> 10, l = row & 1023;
        int h = l >> 5, w = l & 31;
        int c = col >> 8, p = (col >> 4) & 15, q = col & 15;
        P[i] = f2bf(x[((size_t)(b * 3 + c) * 512 + (h * 16 + p)) * 512 + (w * 16 + q)]);
        return;
    }
    i -= 6291456;
    if (i < 147456) { wp[i] = f2bf(patch_w[i]); return; }
    i -= 147456;
    if (i < 147456) { wi[i] = f2bf(in_proj_w[i]); return; }
    i -= 147456;
    if (i < 73728) { wo[i] = f2bf(out_proj_w[i]); return; }
    i -= 73728;
    if (i < 3145728) {                          // deconv_w -> W2[(p16+q)*64+k][c]
        int c = i % 192, np = i / 192;
        int k = np & 63, pq = np >> 6;
        W2[i] = f2bf(deconv_w[(size_t)c * 16384 + k * 256 + pq]);
        return;
    }
    i -= 3145728;
    if (i < 9216) {                             // dec_conv_w -> wconv[tap][m16][ch]
        int ch = i & 63, m = (i >> 6) & 15, tap = i >> 10;
        int dy = tap / 3, dx = tap % 3;
        float v = (m < 3) ? dec_conv_w[((m * 64 + ch) * 3 + dy) * 3 + dx] : 0.f;
        wconv[i] = f2bf(v);
        return;
    }
    i -= 9216;
    {                                           // wxd (416 x 384)
        int col = i % 384, row = i / 384;
        float v;
        if (row < 384) {
            v = 0.f;
            #pragma unroll
            for (int j = 0; j < 12; ++j)
                v = fmaf(dtw[row * 12 + j], xpw[j * 384 + col], v);
        } else {
            v = xpw[(row - 384 + 12) * 384 + col];
        }
        wxd[i] = f2bf(v);
    }
}

// ---------------- depthwise causal conv1d + silu (bf16 in/out) --------------
__global__ __launch_bounds__(256) void conv1d_silu(const unsigned short* __restrict__ xz,
                                                   const float* __restrict__ cw,
                                                   const float* __restrict__ cb,
                                                   unsigned short* __restrict__ u16)
{
    int idx = blockIdx.x * 256 + threadIdx.x;   // 8192*384
    int d = idx % 384;
    int row = idx / 384;
    int l = row & 1023;
    float acc = cb[d];
    #pragma unroll
    for (int j = 0; j < 4; ++j) {
        int ll = l - 3 + j;
        if (ll >= 0) acc += bf2f(xz[(size_t)(row - 3 + j) * 768 + d]) * cw[d * 4 + j];
    }
    float s = acc / (1.f + __expf(-acc));
    u16[idx] = f2bf(s);
}

// ---------------- selective scan, 3-pass: 32 chunks of 32 -------------------
__global__ __launch_bounds__(256) void ssm_pass1(const float* __restrict__ delta,
                                                 const float* __restrict__ bc,
                                                 const unsigned short* __restrict__ u,
                                                 const float* __restrict__ A_log,
                                                 float* __restrict__ Pc,
                                                 float* __restrict__ Hc)
{
    const int tid = threadIdx.x;
    const int n4 = tid & 3, dloc = tid >> 2;
    const int c = blockIdx.x, dg = blockIdx.y, b = blockIdx.z;
    const int d = dg * 64 + dloc;
    const int blk = (b * 6 + dg) * 32 + c;
    f32x4 A4 = *(const f32x4*)(A_log + d * 16 + n4 * 4);
    float Aa[4];
    #pragma unroll
    for (int j = 0; j < 4; ++j) Aa[j] = -__expf(A4[j]);
    const float* dp = delta + (size_t)(b * 1024) * 384 + d;
    const unsigned short* up = u + (size_t)(b * 1024) * 384 + d;
    const float* bp = bc    + (size_t)(b * 1024) * 32;
    float P[4] = {1.f, 1.f, 1.f, 1.f}, H[4] = {0.f, 0.f, 0.f, 0.f};
    const int l0 = c * 32;
    for (int l = l0; l < l0 + 32; ++l) {
        float dlv = dp[(size_t)l * 384];
        float ulv = bf2f(up[(size_t)l * 384]);
        f32x4 B4 = *(const f32x4*)(bp + (size_t)l * 32 + n4 * 4);
        float du = dlv * ulv;
        #pragma unroll
        for (int j = 0; j < 4; ++j) {
            float a = __expf(dlv * Aa[j]);
            P[j] *= a;
            H[j] = fmaf(a, H[j], du * B4[j]);
        }
    }
    size_t o = ((size_t)blk * 256 + tid) * 4;
    *(f32x4*)(Pc + o) = (f32x4){P[0], P[1], P[2], P[3]};
    *(f32x4*)(Hc + o) = (f32x4){H[0], H[1], H[2], H[3]};
}

__global__ __launch_bounds__(256) void ssm_pass2(const float* __restrict__ Pc,
                                                 const float* __restrict__ Hc,
                                                 float* __restrict__ h0c)
{
    int t = blockIdx.x * 256 + threadIdx.x;    // 49152
    int grp = t >> 10, dn = t & 1023;
    float h = 0.f;
    #pragma unroll
    for (int c = 0; c < 32; ++c) {
        size_t idx = ((size_t)(grp * 32 + c)) * 1024 + dn;
        h0c[idx] = h;
        h = fmaf(Pc[idx], h, Hc[idx]);
    }
}

__global__ __launch_bounds__(256) void ssm_pass3(const float* __restrict__ delta,
                                                 const float* __restrict__ bc,
                                                 const unsigned short* __restrict__ u,
                                                 const unsigned short* __restrict__ xz,
                                                 const float* __restrict__ A_log,
                                                 const float* __restrict__ Dp,
                                                 const float* __restrict__ h0c,
                                                 unsigned short* __restrict__ y16)
{
    const int tid = threadIdx.x;
    const int n4 = tid & 3, dloc = tid >> 2;
    const int c = blockIdx.x, dg = blockIdx.y, b = blockIdx.z;
    const int d = dg * 64 + dloc;
    const int blk = (b * 6 + dg) * 32 + c;
    f32x4 A4 = *(const f32x4*)(A_log + d * 16 + n4 * 4);
    float Aa[4];
    #pragma unroll
    for (int j = 0; j < 4; ++j) Aa[j] = -__expf(A4[j]);
    float Dv = Dp[d];
    const float* dp = delta + (size_t)(b * 1024) * 384 + d;
    const unsigned short* up = u + (size_t)(b * 1024) * 384 + d;
    const float* bp = bc    + (size_t)(b * 1024) * 32;
    const unsigned short* zp = xz + (size_t)(b * 1024) * 768 + 384 + d;
    unsigned short* yp = y16 + (size_t)(b * 1024) * 384 + d;
    f32x4 h4 = *(const f32x4*)(h0c + ((size_t)blk * 256 + tid) * 4);
    float H[4] = {h4[0], h4[1], h4[2], h4[3]};
    const int l0 = c * 32;
    for (int l = l0; l < l0 + 32; ++l) {
        float dlv = dp[(size_t)l * 384];
        float ulv = bf2f(up[(size_t)l * 384]);
        f32x4 B4 = *(const f32x4*)(bp + (size_t)l * 32 + n4 * 4);
        f32x4 C4 = *(const f32x4*)(bp + (size_t)l * 32 + 16 + n4 * 4);
        float du = dlv * ulv;
        float part = 0.f;
        #pragma unroll
        for (int j = 0; j < 4; ++j) {
            float a = __expf(dlv * Aa[j]);
            H[j] = fmaf(a, H[j], du * B4[j]);
            part = fmaf(H[j], C4[j], part);
        }
        part += __shfl_xor(part, 1, 4);
        part += __shfl_xor(part, 2, 4);
        if (n4 == 0) {
            float z = bf2f(zp[(size_t)l * 768]);
            float sz = z / (1.f + __expf(-z));
            yp[(size_t)l * 384] = f2bf((part + ulv * Dv) * sz);
        }
    }
}

// ---------------- MFMA 3x3 conv (64->3) + bias + sigmoid, 4 batches ---------
__global__ __launch_bounds__(256) void decconv_mfma(
    const unsigned short* __restrict__ Db, const unsigned short* __restrict__ wconv,
    const float* __restrict__ dcb, float* __restrict__ out, int base_b)
{
    __shared__ unsigned short ds[18 * 18 * 72];
    const int t = threadIdx.x;
    const int pidx = blockIdx.x;
    const int bb = blockIdx.y;
    const int b = base_b + bb;
    const unsigned short* Dbb = Db + (size_t)bb * 16777216;
    const int ph = pidx >> 5, pw = pidx & 31;
    const uint4 z4 = {0, 0, 0, 0};

    const unsigned short* base = Dbb + ((size_t)pidx << 14);
    #pragma unroll
    for (int s = 0; s < 8; ++s) {
        int f = s * 256 + t;
        int k8 = f & 7, pq = f >> 3;
        *(uint4*)&ds[(((pq >> 4) + 1) * 18 + (pq & 15) + 1) * 72 + k8 * 8] =
            *(const uint4*)(base + pq * 64 + k8 * 8);
    }
    {
        int k8 = t & 7, e = (t >> 3) & 15;
        if (t < 128) {
            uint4 v = z4;
            if (ph > 0) v = *(const uint4*)(Dbb + ((size_t)(pidx - 32) << 14) + (240 + e) * 64 + k8 * 8);
            *(uint4*)&ds[(0 * 18 + e + 1) * 72 + k8 * 8] = v;
        } else {
            uint4 v = z4;
            if (ph < 31) v = *(const uint4*)(Dbb + ((size_t)(pidx + 32) << 14) + e * 64 + k8 * 8);
            *(uint4*)&ds[(17 * 18 + e + 1) * 72 + k8 * 8] = v;
        }
        if (t < 128) {
            uint4 v = z4;
            if (pw > 0) v = *(const uint4*)(Dbb + ((size_t)(pidx - 1) << 14) + (e * 16 + 15) * 64 + k8 * 8);
            *(uint4*)&ds[((e + 1) * 18 + 0) * 72 + k8 * 8] = v;
        } else {
            uint4 v = z4;
            if (pw < 31) v = *(const uint4*)(Dbb + ((size_t)(pidx + 1) << 14) + (e * 16) * 64 + k8 * 8);
            *(uint4*)&ds[((e + 1) * 18 + 17) * 72 + k8 * 8] = v;
        }
        if (t < 32) {
            int c = t >> 3;
            int dh = (c >> 1) * 2 - 1, dw = (c & 1) * 2 - 1;
            int nh = ph + dh, nw = pw + dw;
            int sp = dh < 0 ? 15 : 0, sq = dw < 0 ? 15 : 0;
            uint4 v = z4;
            if (nh >= 0 && nh < 32 && nw >= 0 && nw < 32)
                v = *(const uint4*)(Dbb + ((size_t)(nh * 32 + nw) << 14) + (sp * 16 + sq) * 64 + k8 * 8);
            int dy = dh < 0 ? 0 : 17, dx = dw < 0 ? 0 : 17;
            *(uint4*)&ds[(dy * 18 + dx) * 72 + k8 * 8] = v;
        }
    }
    __syncthreads();

    const int wave = t >> 6, lane = t & 63;
    const int quad = lane >> 4, lr = lane & 15;
    f32x4 acc[4];
    #pragma unroll
    for (int i = 0; i < 4; ++i) acc[i] = (f32x4){0.f, 0.f, 0.f, 0.f};

    #pragma unroll
    for (int tap = 0; tap < 9; ++tap) {
        const int dy = tap / 3, dx = tap % 3;
        bf16x8 a0 = *(const bf16x8*)(wconv + (tap * 16 + lr) * 64 + quad * 8);
        bf16x8 a1 = *(const bf16x8*)(wconv + (tap * 16 + lr) * 64 + 32 + quad * 8);
        #pragma unroll
        for (int i = 0; i < 4; ++i) {
            int p = wave * 4 + i;
            const unsigned short* cell = &ds[((p + dy) * 18 + lr + dx) * 72];
            bf16x8 b0 = *(const bf16x8*)(cell + quad * 8);
            bf16x8 b1 = *(const bf16x8*)(cell + 32 + quad * 8);
            acc[i] = __builtin_amdgcn_mfma_f32_16x16x32_bf16(a0, b0, acc[i], 0, 0, 0);
            acc[i] = __builtin_amdgcn_mfma_f32_16x16x32_bf16(a1, b1, acc[i], 0, 0, 0);
        }
    }

    if (quad == 0) {
        float b0 = dcb[0], b1 = dcb[1], b2 = dcb[2];
        #pragma unroll
        for (int i = 0; i < 4; ++i) {
            int Y = ph * 16 + wave * 4 + i, X = pw * 16 + lr;
            size_t o = (size_t)(b * 3) * 262144 + (size_t)Y * 512 + X;
            out[o]          = 1.f / (1.f + __expf(-(acc[i][0] + b0)));
            out[o + 262144] = 1.f / (1.f + __expf(-(acc[i][1] + b1)));
            out[o + 524288] = 1.f / (1.f + __expf(-(acc[i][2] + b2)));
        }
    }
}

// ---------------------------------------------------------------------------
// Workspace layout (float units) — FULLY RE-AUDITED sizes:
//   8192x768 bf16 = 3,145,728 f; 8192x384 bf16 = 1,572,864 f;
//   8192x192 bf16 =   786,432 f; 16384x192 bf16 = 1,572,864 f.
// Encoder scratch [0, 15204352). Decoder Db bf16 4-batch = [0, 33554432).
// Persistent weights at 33554432..36180224 < 67108864 (ws = 256 MiB).
// ---------------------------------------------------------------------------
#define WS_DELTA    0            // f32 8192x384 (3145728 f); P16 aliases (dead after step 2)
#define WS_SEQ16    3145728      // bf16 8192x192 (786432 f) -> 3932160, dead after in_proj
#define WS_XZ16     3932160      // bf16 8192x768 (3145728 f) -> 7077888
#define WS_U16      7077888      // bf16 8192x384 (1572864 f) -> 8650752
#define WS_Y16      8650752      // bf16 8192x384 (1572864 f) -> 10223616
#define WS_BC       10223616     // f32 8192x32 (262144 f) -> 10485760
#define WS_PC       10485760     // 1572864 -> 12058624
#define WS_HC       12058624     // 1572864 -> 13631488
#define WS_H0C      13631488     // 1572864 -> 15204352
#define WS_WBASE    33554432     // persistent weights above Db

extern "C" void kernel_launch(void* const* d_in, const int* in_sizes, int n_in,
                              void* d_out, int out_size, void* d_ws, size_t ws_size,
                              hipStream_t stream)
{
    const float* x         = (const float*)d_in[0];
    const float* patch_w   = (const float*)d_in[1];
    const float* patch_b   = (const float*)d_in[2];
    const float* in_proj_w = (const float*)d_in[3];
    const float* conv1d_w  = (const float*)d_in[4];
    const float* conv1d_b  = (const float*)d_in[5];
    const float* x_proj_w  = (const float*)d_in[6];
    const float* dt_proj_w = (const float*)d_in[7];
    const float* dt_proj_b = (const float*)d_in[8];
    const float* A_log     = (const float*)d_in[9];
    const float* Dp        = (const float*)d_in[10];
    const float* out_proj_w= (const float*)d_in[11];
    const float* deconv_w  = (const float*)d_in[12];
    const float* deconv_b  = (const float*)d_in[13];
    const float* dec_conv_w= (const float*)d_in[14];
    const float* dec_conv_b= (const float*)d_in[15];
    float* out = (float*)d_out;
    float* ws  = (float*)d_ws;

    unsigned short* P16   = (unsigned short*)(ws + WS_DELTA);
    float*          delta = ws + WS_DELTA;
    unsigned short* seq16 = (unsigned short*)(ws + WS_SEQ16);
    unsigned short* xz16  = (unsigned short*)(ws + WS_XZ16);
    unsigned short* u16   = (unsigned short*)(ws + WS_U16);
    unsigned short* y16   = (unsigned short*)(ws + WS_Y16);
    float*          bc    = ws + WS_BC;
    float*          Pc    = ws + WS_PC;
    float*          Hc    = ws + WS_HC;
    float*          h0c   = ws + WS_H0C;
    unsigned short* Db16  = (unsigned short*)(ws);
    // persistent weights (float offsets from WBASE):
    unsigned short* seqo_b= (unsigned short*)(ws + WS_WBASE);              // 786432 f
    unsigned short* W2b   = (unsigned short*)(ws + WS_WBASE + 786432);     // 1572864 f
    unsigned short* wconv = (unsigned short*)(ws + WS_WBASE + 2359296);    // 2304 f
    unsigned short* wp16  = (unsigned short*)(ws + WS_WBASE + 2361600);    // 73728 f
    unsigned short* wi16  = (unsigned short*)(ws + WS_WBASE + 2435328);    // 73728 f
    unsigned short* wo16  = (unsigned short*)(ws + WS_WBASE + 2509056);    // 36864 f
    unsigned short* wxd   = (unsigned short*)(ws + WS_WBASE + 2545920);    // 79872 f -> 2625792

    // 1. fused prep: im2col + all weight transforms
    prep_all<<<38964, 256, 0, stream>>>(x, P16, patch_w, wp16, in_proj_w, wi16,
                                        out_proj_w, wo16, deconv_w, W2b,
                                        dec_conv_w, wconv, dt_proj_w, x_proj_w, wxd);
    // 2. patch embedding -> seq16 bf16
    gemm_mfma_flex<<<dim3(2, 64), 256, 0, stream>>>(P16, wp16, seq16, patch_b,
                                                    8192, 192, 768, 1);
    // 3. in_proj -> xz16 bf16
    gemm_mfma_flex<<<dim3(6, 64), 256, 0, stream>>>(seq16, wi16, xz16, nullptr,
                                                    8192, 768, 192, 1);
    // 4. conv1d + silu -> u16
    conv1d_silu<<<12288, 256, 0, stream>>>(xz16, conv1d_w, conv1d_b, u16);
    // 5. combined x_proj+dt_proj -> delta (softplus) + bc
    gemm_xd<<<dim3(4, 64), 256, 0, stream>>>(u16, wxd, delta, bc, dt_proj_b);
    // 6. selective scan (3-pass, 32 chunks of 32)
    ssm_pass1<<<dim3(32, 6, 8), 256, 0, stream>>>(delta, bc, u16, A_log, Pc, Hc);
    ssm_pass2<<<192, 256, 0, stream>>>(Pc, Hc, h0c);
    ssm_pass3<<<dim3(32, 6, 8), 256, 0, stream>>>(delta, bc, u16, xz16, A_log, Dp, h0c, y16);
    // 7. out_proj -> seqo_b bf16
    gemm_mfma_flex<<<dim3(2, 64), 256, 0, stream>>>(y16, wo16, seqo_b, nullptr,
                                                    8192, 192, 384, 1);
    // 8. decoder: 2 groups x (4-batch MFMA GEMM -> 4-batch MFMA conv+sigmoid)
    for (int g = 0; g < 2; ++g) {
        gemm_mfma_relu_bf16<<<dim3(128, 8, 4), 256, 0, stream>>>(
            seqo_b, W2b, Db16, deconv_b, g * 4);
        decconv_mfma<<<dim3(1024, 4), 256, 0, stream>>>(Db16, wconv, dec_conv_b, out, g * 4);
    }
}

// Round 11
// 533.276 us; speedup vs baseline: 1.0089x; 1.0089x over previous
//
#include <hip/hip_runtime.h>
#include <math.h>

// ---------------------------------------------------------------------------
// VisionMambaDenoiser. Round 11: decoder GEMM epilogue made single-pass
// (full 128x128 C-tile in LDS, no post-store barriers). R10 evidence: the
// dispatch time was invariant to batch count (68.5 us at 2 AND 4 batches,
// 1.93 TB/s writes, 6.4 waves/CU) -> per-block vmcnt(0) drains at the two
// post-store __syncthreads were serializing blocks. Everything else = R10.
// ---------------------------------------------------------------------------

typedef short bf16x8 __attribute__((ext_vector_type(8)));
typedef float f32x4 __attribute__((ext_vector_type(4)));

__device__ inline unsigned short f2bf(float f) {
    unsigned int u = __float_as_uint(f);
    unsigned int r = (u + 0x7fff + ((u >> 16) & 1)) >> 16;   // RNE
    return (unsigned short)r;
}
__device__ inline float bf2f(unsigned short s) {
    return __uint_as_float(((unsigned int)s) << 16);
}

// ---------------- flexible bf16 MFMA GEMM: C = A @ W^T (+bias) --------------
__global__ __launch_bounds__(256) void gemm_mfma_flex(
    const unsigned short* __restrict__ A, const unsigned short* __restrict__ W,
    void* __restrict__ Cout, const float* __restrict__ bias,
    int M, int N, int K, int out_bf16)
{
    __shared__ unsigned short As[128][40];
    __shared__ unsigned short Bs[128][40];
    const int tid = threadIdx.x;
    const int wave = tid >> 6, lane = tid & 63;
    const int wm = (wave & 1) * 64, wn = (wave >> 1) * 64;
    const int m0 = blockIdx.y * 128, n0 = blockIdx.x * 128;
    const int quad = lane >> 4, lr = lane & 15;
    const uint4 z4 = {0, 0, 0, 0};

    f32x4 acc[4][4];
    #pragma unroll
    for (int i = 0; i < 4; ++i)
        #pragma unroll
        for (int j = 0; j < 4; ++j)
            acc[i][j] = (f32x4){0.f, 0.f, 0.f, 0.f};

    const int r = tid >> 2, kq = tid & 3;
    for (int k0 = 0; k0 < K; k0 += 32) {
        #pragma unroll
        for (int half = 0; half < 2; ++half) {
            int rr = r + half * 64;
            *(uint4*)(&As[rr][kq * 8]) =
                *(const uint4*)(A + (size_t)(m0 + rr) * K + k0 + kq * 8);
            uint4 bv = z4;
            if (n0 + rr < N)
                bv = *(const uint4*)(W + (size_t)(n0 + rr) * K + k0 + kq * 8);
            *(uint4*)(&Bs[rr][kq * 8]) = bv;
        }
        __syncthreads();
        bf16x8 af[4], bfr[4];
        #pragma unroll
        for (int i = 0; i < 4; ++i) af[i] = *(const bf16x8*)(&As[wm + i * 16 + lr][quad * 8]);
        #pragma unroll
        for (int j = 0; j < 4; ++j) bfr[j] = *(const bf16x8*)(&Bs[wn + j * 16 + lr][quad * 8]);
        #pragma unroll
        for (int i = 0; i < 4; ++i)
            #pragma unroll
            for (int j = 0; j < 4; ++j)
                acc[i][j] = __builtin_amdgcn_mfma_f32_16x16x32_bf16(af[i], bfr[j], acc[i][j], 0, 0, 0);
        __syncthreads();
    }

    #pragma unroll
    for (int i = 0; i < 4; ++i) {
        int gm = m0 + wm + i * 16 + quad * 4;
        #pragma unroll
        for (int j = 0; j < 4; ++j) {
            int gn = n0 + wn + j * 16 + lr;
            if (gn >= N) continue;
            float bv = bias ? bias[gn] : 0.f;
            #pragma unroll
            for (int rr = 0; rr < 4; ++rr) {
                float v = acc[i][j][rr] + bv;
                if (out_bf16) ((unsigned short*)Cout)[(size_t)(gm + rr) * N + gn] = f2bf(v);
                else          ((float*)Cout)[(size_t)(gm + rr) * N + gn] = v;
            }
        }
    }
}

// ---------------- combined x_proj+dt_proj GEMM (N=416, K=384) ---------------
__global__ __launch_bounds__(256) void gemm_xd(
    const unsigned short* __restrict__ A, const unsigned short* __restrict__ W,
    float* __restrict__ delta, float* __restrict__ bc,
    const float* __restrict__ dtb)
{
    __shared__ unsigned short As[128][40];
    __shared__ unsigned short Bs[128][40];
    const int N = 416, K = 384;
    const int tid = threadIdx.x;
    const int wave = tid >> 6, lane = tid & 63;
    const int wm = (wave & 1) * 64, wn = (wave >> 1) * 64;
    const int m0 = blockIdx.y * 128, n0 = blockIdx.x * 128;
    const int quad = lane >> 4, lr = lane & 15;
    const uint4 z4 = {0, 0, 0, 0};

    f32x4 acc[4][4];
    #pragma unroll
    for (int i = 0; i < 4; ++i)
        #pragma unroll
        for (int j = 0; j < 4; ++j)
            acc[i][j] = (f32x4){0.f, 0.f, 0.f, 0.f};

    const int r = tid >> 2, kq = tid & 3;
    for (int k0 = 0; k0 < K; k0 += 32) {
        #pragma unroll
        for (int half = 0; half < 2; ++half) {
            int rr = r + half * 64;
            *(uint4*)(&As[rr][kq * 8]) =
                *(const uint4*)(A + (size_t)(m0 + rr) * K + k0 + kq * 8);
            uint4 bv = z4;
            if (n0 + rr < N)
                bv = *(const uint4*)(W + (size_t)(n0 + rr) * K + k0 + kq * 8);
            *(uint4*)(&Bs[rr][kq * 8]) = bv;
        }
        __syncthreads();
        bf16x8 af[4], bfr[4];
        #pragma unroll
        for (int i = 0; i < 4; ++i) af[i] = *(const bf16x8*)(&As[wm + i * 16 + lr][quad * 8]);
        #pragma unroll
        for (int j = 0; j < 4; ++j) bfr[j] = *(const bf16x8*)(&Bs[wn + j * 16 + lr][quad * 8]);
        #pragma unroll
        for (int i = 0; i < 4; ++i)
            #pragma unroll
            for (int j = 0; j < 4; ++j)
                acc[i][j] = __builtin_amdgcn_mfma_f32_16x16x32_bf16(af[i], bfr[j], acc[i][j], 0, 0, 0);
        __syncthreads();
    }

    #pragma unroll
    for (int i = 0; i < 4; ++i) {
        int gm = m0 + wm + i * 16 + quad * 4;
        #pragma unroll
        for (int j = 0; j < 4; ++j) {
            int gn = n0 + wn + j * 16 + lr;
            if (gn >= N) continue;
            #pragma unroll
            for (int rr = 0; rr < 4; ++rr) {
                float v = acc[i][j][rr];
                if (gn < 384) {
                    v += dtb[gn];
                    v = (v > 20.f) ? v : log1pf(__expf(v));
                    delta[(size_t)(gm + rr) * 384 + gn] = v;
                } else {
                    bc[(size_t)(gm + rr) * 32 + gn - 384] = v;
                }
            }
        }
    }
}

// ---------------- decoder MFMA GEMM (4 batches): Db=bf16(relu(A@W^T+b)) -----
// Single-pass epilogue: full 128x128 C-tile in LDS, NO post-store barriers
// (the old 2-half epilogue forced two vmcnt(0) drains per block).
__global__ __launch_bounds__(256) void gemm_mfma_relu_bf16(
    const unsigned short* __restrict__ A0, const unsigned short* __restrict__ W,
    unsigned short* __restrict__ C0, const float* __restrict__ bias, int base_b)
{
    __shared__ unsigned short smem[17408];       // As|Bs (10240) U Ct (128x136)
    unsigned short* As = smem;
    unsigned short* Bs = smem + 5120;
    const int N = 16384, K = 192;
    const int tid = threadIdx.x;
    const int wave = tid >> 6, lane = tid & 63;
    const int wm = (wave & 1) * 64, wn = (wave >> 1) * 64;
    const int m0 = blockIdx.y * 128, n0 = blockIdx.x * 128;
    const int z = blockIdx.z;
    const unsigned short* A = A0 + (size_t)(base_b + z) * 1024 * 192;
    unsigned short* C = C0 + (size_t)z * 16777216;
    const int quad = lane >> 4, lr = lane & 15;

    f32x4 acc[4][4];
    #pragma unroll
    for (int i = 0; i < 4; ++i)
        #pragma unroll
        for (int j = 0; j < 4; ++j)
            acc[i][j] = (f32x4){0.f, 0.f, 0.f, 0.f};

    const int r = tid >> 2, kq = tid & 3;
    for (int k0 = 0; k0 < K; k0 += 32) {
        #pragma unroll
        for (int half = 0; half < 2; ++half) {
            int rr = r + half * 64;
            *(uint4*)(&As[rr * 40 + kq * 8]) =
                *(const uint4*)(A + (size_t)(m0 + rr) * K + k0 + kq * 8);
            *(uint4*)(&Bs[rr * 40 + kq * 8]) =
                *(const uint4*)(W + (size_t)(n0 + rr) * K + k0 + kq * 8);
        }
        __syncthreads();
        bf16x8 af[4], bfr[4];
        #pragma unroll
        for (int i = 0; i < 4; ++i) af[i] = *(const bf16x8*)(&As[(wm + i * 16 + lr) * 40 + quad * 8]);
        #pragma unroll
        for (int j = 0; j < 4; ++j) bfr[j] = *(const bf16x8*)(&Bs[(wn + j * 16 + lr) * 40 + quad * 8]);
        #pragma unroll
        for (int i = 0; i < 4; ++i)
            #pragma unroll
            for (int j = 0; j < 4; ++j)
                acc[i][j] = __builtin_amdgcn_mfma_f32_16x16x32_bf16(af[i], bfr[j], acc[i][j], 0, 0, 0);
        __syncthreads();
    }

    // single-pass epilogue: all waves write Ct, one barrier, stores, no drain
    unsigned short* Ct = smem;                   // 128*136 = 17408 ushorts
    #pragma unroll
    for (int i = 0; i < 4; ++i) {
        int lrow = wm + i * 16 + quad * 4;
        #pragma unroll
        for (int j = 0; j < 4; ++j) {
            int lcol = wn + j * 16 + lr;
            float bv = bias[(n0 + lcol) & 63];
            #pragma unroll
            for (int rr = 0; rr < 4; ++rr) {
                float v = fmaxf(acc[i][j][rr] + bv, 0.f);
                Ct[(lrow + rr) * 136 + lcol] = f2bf(v);
            }
        }
    }
    __syncthreads();                             // LDS-only drain (vmem idle)
    #pragma unroll
    for (int p = 0; p < 8; ++p) {
        int idx = p * 256 + tid;                 // 0..2047
        int row = idx >> 4, cg = idx & 15;
        *(uint4*)(C + (size_t)(m0 + row) * N + n0 + cg * 8) =
            *(const uint4*)(&Ct[row * 136 + cg * 8]);
    }
    // no trailing barrier: stores drain while other blocks compute
}

// ---------------- fused prep: im2col + all weight transforms ----------------
__global__ __launch_bounds__(256) void prep_all(
    const float* __restrict__ x, unsigned short* __restrict__ P,
    const float* __restrict__ patch_w, unsigned short* __restrict__ wp,
    const float* __restrict__ in_proj_w, unsigned short* __restrict__ wi,
    const float* __restrict__ out_proj_w, unsigned short* __restrict__ wo,
    const float* __restrict__ deconv_w, unsigned short* __restrict__ W2,
    const float* __restrict__ dec_conv_w, unsigned short* __restrict__ wconv,
    const float* __restrict__ dtw, const float* __restrict__ xpw,
    unsigned short* __restrict__ wxd)
{
    int i = blockIdx.x * 256 + threadIdx.x;     // 9974784 total
    if (i < 6291456) {
        int col = i % 768, row = i / 768;
        int b = row >> 10, l = row & 1023;
        int h = l >> 5, w = l & 31;
        int c = col >> 8, p = (col >> 4) & 15, q = col & 15;
        P[i] = f2bf(x[((size_t)(b * 3 + c) * 512 + (h * 16 + p)) * 512 + (w * 16 + q)]);
        return;
    }
    i -= 6291456;
    if (i < 147456) { wp[i] = f2bf(patch_w[i]); return; }
    i -= 147456;
    if (i < 147456) { wi[i] = f2bf(in_proj_w[i]); return; }
    i -= 147456;
    if (i < 73728) { wo[i] = f2bf(out_proj_w[i]); return; }
    i -= 73728;
    if (i < 3145728) {                          // deconv_w -> W2[(p16+q)*64+k][c]
        int c = i % 192, np = i / 192;
        int k = np & 63, pq = np >> 6;
        W2[i] = f2bf(deconv_w[(size_t)c * 16384 + k * 256 + pq]);
        return;
    }
    i -= 3145728;
    if (i < 9216) {                             // dec_conv_w -> wconv[tap][m16][ch]
        int ch = i & 63, m = (i >> 6) & 15, tap = i >> 10;
        int dy = tap / 3, dx = tap % 3;
        float v = (m < 3) ? dec_conv_w[((m * 64 + ch) * 3 + dy) * 3 + dx] : 0.f;
        wconv[i] = f2bf(v);
        return;
    }
    i -= 9216;
    {                                           // wxd (416 x 384)
        int col = i % 384, row = i / 384;
        float v;
        if (row < 384) {
            v = 0.f;
            #pragma unroll
            for (int j = 0; j < 12; ++j)
                v = fmaf(dtw[row * 12 + j], xpw[j * 384 + col], v);
        } else {
            v = xpw[(row - 384 + 12) * 384 + col];
        }
        wxd[i] = f2bf(v);
    }
}

// ---------------- depthwise causal conv1d + silu (bf16 in/out) --------------
__global__ __launch_bounds__(256) void conv1d_silu(const unsigned short* __restrict__ xz,
                                                   const float* __restrict__ cw,
                                                   const float* __restrict__ cb,
                                                   unsigned short* __restrict__ u16)
{
    int idx = blockIdx.x * 256 + threadIdx.x;   // 8192*384
    int d = idx % 384;
    int row = idx / 384;
    int l = row & 1023;
    float acc = cb[d];
    #pragma unroll
    for (int j = 0; j < 4; ++j) {
        int ll = l - 3 + j;
        if (ll >= 0) acc += bf2f(xz[(size_t)(row - 3 + j) * 768 + d]) * cw[d * 4 + j];
    }
    float s = acc / (1.f + __expf(-acc));
    u16[idx] = f2bf(s);
}

// ---------------- selective scan, 3-pass: 32 chunks of 32 -------------------
__global__ __launch_bounds__(256) void ssm_pass1(const float* __restrict__ delta,
                                                 const float* __restrict__ bc,
                                                 const unsigned short* __restrict__ u,
                                                 const float* __restrict__ A_log,
                                                 float* __restrict__ Pc,
                                                 float* __restrict__ Hc)
{
    const int tid = threadIdx.x;
    const int n4 = tid & 3, dloc = tid >> 2;
    const int c = blockIdx.x, dg = blockIdx.y, b = blockIdx.z;
    const int d = dg * 64 + dloc;
    const int blk = (b * 6 + dg) * 32 + c;
    f32x4 A4 = *(const f32x4*)(A_log + d * 16 + n4 * 4);
    float Aa[4];
    #pragma unroll
    for (int j = 0; j < 4; ++j) Aa[j] = -__expf(A4[j]);
    const float* dp = delta + (size_t)(b * 1024) * 384 + d;
    const unsigned short* up = u + (size_t)(b * 1024) * 384 + d;
    const float* bp = bc    + (size_t)(b * 1024) * 32;
    float P[4] = {1.f, 1.f, 1.f, 1.f}, H[4] = {0.f, 0.f, 0.f, 0.f};
    const int l0 = c * 32;
    for (int l = l0; l < l0 + 32; ++l) {
        float dlv = dp[(size_t)l * 384];
        float ulv = bf2f(up[(size_t)l * 384]);
        f32x4 B4 = *(const f32x4*)(bp + (size_t)l * 32 + n4 * 4);
        float du = dlv * ulv;
        #pragma unroll
        for (int j = 0; j < 4; ++j) {
            float a = __expf(dlv * Aa[j]);
            P[j] *= a;
            H[j] = fmaf(a, H[j], du * B4[j]);
        }
    }
    size_t o = ((size_t)blk * 256 + tid) * 4;
    *(f32x4*)(Pc + o) = (f32x4){P[0], P[1], P[2], P[3]};
    *(f32x4*)(Hc + o) = (f32x4){H[0], H[1], H[2], H[3]};
}

__global__ __launch_bounds__(256) void ssm_pass2(const float* __restrict__ Pc,
                                                 const float* __restrict__ Hc,
                                                 float* __restrict__ h0c)
{
    int t = blockIdx.x * 256 + threadIdx.x;    // 49152
    int grp = t >> 10, dn = t & 1023;
    float h = 0.f;
    #pragma unroll
    for (int c = 0; c < 32; ++c) {
        size_t idx = ((size_t)(grp * 32 + c)) * 1024 + dn;
        h0c[idx] = h;
        h = fmaf(Pc[idx], h, Hc[idx]);
    }
}

__global__ __launch_bounds__(256) void ssm_pass3(const float* __restrict__ delta,
                                                 const float* __restrict__ bc,
                                                 const unsigned short* __restrict__ u,
                                                 const unsigned short* __restrict__ xz,
                                                 const float* __restrict__ A_log,
                                                 const float* __restrict__ Dp,
                                                 const float* __restrict__ h0c,
                                                 unsigned short* __restrict__ y16)
{
    const int tid = threadIdx.x;
    const int n4 = tid & 3, dloc = tid >> 2;
    const int c = blockIdx.x, dg = blockIdx.y, b = blockIdx.z;
    const int d = dg * 64 + dloc;
    const int blk = (b * 6 + dg) * 32 + c;
    f32x4 A4 = *(const f32x4*)(A_log + d * 16 + n4 * 4);
    float Aa[4];
    #pragma unroll
    for (int j = 0; j < 4; ++j) Aa[j] = -__expf(A4[j]);
    float Dv = Dp[d];
    const float* dp = delta + (size_t)(b * 1024) * 384 + d;
    const unsigned short* up = u + (size_t)(b * 1024) * 384 + d;
    const float* bp = bc    + (size_t)(b * 1024) * 32;
    const unsigned short* zp = xz + (size_t)(b * 1024) * 768 + 384 + d;
    unsigned short* yp = y16 + (size_t)(b * 1024) * 384 + d;
    f32x4 h4 = *(const f32x4*)(h0c + ((size_t)blk * 256 + tid) * 4);
    float H[4] = {h4[0], h4[1], h4[2], h4[3]};
    const int l0 = c * 32;
    for (int l = l0; l < l0 + 32; ++l) {
        float dlv = dp[(size_t)l * 384];
        float ulv = bf2f(up[(size_t)l * 384]);
        f32x4 B4 = *(const f32x4*)(bp + (size_t)l * 32 + n4 * 4);
        f32x4 C4 = *(const f32x4*)(bp + (size_t)l * 32 + 16 + n4 * 4);
        float du = dlv * ulv;
        float part = 0.f;
        #pragma unroll
        for (int j = 0; j < 4; ++j) {
            float a = __expf(dlv * Aa[j]);
            H[j] = fmaf(a, H[j], du * B4[j]);
            part = fmaf(H[j], C4[j], part);
        }
        part += __shfl_xor(part, 1, 4);
        part += __shfl_xor(part, 2, 4);
        if (n4 == 0) {
            float z = bf2f(zp[(size_t)l * 768]);
            float sz = z / (1.f + __expf(-z));
            yp[(size_t)l * 384] = f2bf((part + ulv * Dv) * sz);
        }
    }
}

// ---------------- MFMA 3x3 conv (64->3) + bias + sigmoid, 4 batches ---------
__global__ __launch_bounds__(256) void decconv_mfma(
    const unsigned short* __restrict__ Db, const unsigned short* __restrict__ wconv,
    const float* __restrict__ dcb, float* __restrict__ out, int base_b)
{
    __shared__ unsigned short ds[18 * 18 * 72];
    const int t = threadIdx.x;
    const int pidx = blockIdx.x;
    const int bb = blockIdx.y;
    const int b = base_b + bb;
    const unsigned short* Dbb = Db + (size_t)bb * 16777216;
    const int ph = pidx >> 5, pw = pidx & 31;
    const uint4 z4 = {0, 0, 0, 0};

    const unsigned short* base = Dbb + ((size_t)pidx << 14);
    #pragma unroll
    for (int s = 0; s < 8; ++s) {
        int f = s * 256 + t;
        int k8 = f & 7, pq = f >> 3;
        *(uint4*)&ds[(((pq >> 4) + 1) * 18 + (pq & 15) + 1) * 72 + k8 * 8] =
            *(const uint4*)(base + pq * 64 + k8 * 8);
    }
    {
        int k8 = t & 7, e = (t >> 3) & 15;
        if (t < 128) {
            uint4 v = z4;
            if (ph > 0) v = *(const uint4*)(Dbb + ((size_t)(pidx - 32) << 14) + (240 + e) * 64 + k8 * 8);
            *(uint4*)&ds[(0 * 18 + e + 1) * 72 + k8 * 8] = v;
        } else {
            uint4 v = z4;
            if (ph < 31) v = *(const uint4*)(Dbb + ((size_t)(pidx + 32) << 14) + e * 64 + k8 * 8);
            *(uint4*)&ds[(17 * 18 + e + 1) * 72 + k8 * 8] = v;
        }
        if (t < 128) {
            uint4 v = z4;
            if (pw > 0) v = *(const uint4*)(Dbb + ((size_t)(pidx - 1) << 14) + (e * 16 + 15) * 64 + k8 * 8);
            *(uint4*)&ds[((e + 1) * 18 + 0) * 72 + k8 * 8] = v;
        } else {
            uint4 v = z4;
            if (pw < 31) v = *(const uint4*)(Dbb + ((size_t)(pidx + 1) << 14) + (e * 16) * 64 + k8 * 8);
            *(uint4*)&ds[((e + 1) * 18 + 17) * 72 + k8 * 8] = v;
        }
        if (t < 32) {
            int c = t >> 3;
            int dh = (c >> 1) * 2 - 1, dw = (c & 1) * 2 - 1;
            int nh = ph + dh, nw = pw + dw;
            int sp = dh < 0 ? 15 : 0, sq = dw < 0 ? 15 : 0;
            uint4 v = z4;
            if (nh >= 0 && nh < 32 && nw >= 0 && nw < 32)
                v = *(const uint4*)(Dbb + ((size_t)(nh * 32 + nw) << 14) + (sp * 16 + sq) * 64 + k8 * 8);
            int dy = dh < 0 ? 0 : 17, dx = dw < 0 ? 0 : 17;
            *(uint4*)&ds[(dy * 18 + dx) * 72 + k8 * 8] = v;
        }
    }
    __syncthreads();

    const int wave = t >> 6, lane = t & 63;
    const int quad = lane >> 4, lr = lane & 15;
    f32x4 acc[4];
    #pragma unroll
    for (int i = 0; i < 4; ++i) acc[i] = (f32x4){0.f, 0.f, 0.f, 0.f};

    #pragma unroll
    for (int tap = 0; tap < 9; ++tap) {
        const int dy = tap / 3, dx = tap % 3;
        bf16x8 a0 = *(const bf16x8*)(wconv + (tap * 16 + lr) * 64 + quad * 8);
        bf16x8 a1 = *(const bf16x8*)(wconv + (tap * 16 + lr) * 64 + 32 + quad * 8);
        #pragma unroll
        for (int i = 0; i < 4; ++i) {
            int p = wave * 4 + i;
            const unsigned short* cell = &ds[((p + dy) * 18 + lr + dx) * 72];
            bf16x8 b0 = *(const bf16x8*)(cell + quad * 8);
            bf16x8 b1 = *(const bf16x8*)(cell + 32 + quad * 8);
            acc[i] = __builtin_amdgcn_mfma_f32_16x16x32_bf16(a0, b0, acc[i], 0, 0, 0);
            acc[i] = __builtin_amdgcn_mfma_f32_16x16x32_bf16(a1, b1, acc[i], 0, 0, 0);
        }
    }

    if (quad == 0) {
        float b0 = dcb[0], b1 = dcb[1], b2 = dcb[2];
        #pragma unroll
        for (int i = 0; i < 4; ++i) {
            int Y = ph * 16 + wave * 4 + i, X = pw * 16 + lr;
            size_t o = (size_t)(b * 3) * 262144 + (size_t)Y * 512 + X;
            out[o]          = 1.f / (1.f + __expf(-(acc[i][0] + b0)));
            out[o + 262144] = 1.f / (1.f + __expf(-(acc[i][1] + b1)));
            out[o + 524288] = 1.f / (1.f + __expf(-(acc[i][2] + b2)));
        }
    }
}

// ---------------------------------------------------------------------------
// Workspace layout (float units) — audited sizes:
//   8192x768 bf16 = 3,145,728 f; 8192x384 bf16 = 1,572,864 f;
//   8192x192 bf16 =   786,432 f; 16384x192 bf16 = 1,572,864 f.
// Encoder scratch [0, 15204352). Decoder Db bf16 4-batch = [0, 33554432).
// Persistent weights at 33554432..36180224 < 67108864 (ws = 256 MiB).
// ---------------------------------------------------------------------------
#define WS_DELTA    0            // f32 8192x384 (3145728 f); P16 aliases (dead after step 2)
#define WS_SEQ16    3145728      // bf16 8192x192 (786432 f) -> 3932160, dead after in_proj
#define WS_XZ16     3932160      // bf16 8192x768 (3145728 f) -> 7077888
#define WS_U16      7077888      // bf16 8192x384 (1572864 f) -> 8650752
#define WS_Y16      8650752      // bf16 8192x384 (1572864 f) -> 10223616
#define WS_BC       10223616     // f32 8192x32 (262144 f) -> 10485760
#define WS_PC       10485760     // 1572864 -> 12058624
#define WS_HC       12058624     // 1572864 -> 13631488
#define WS_H0C      13631488     // 1572864 -> 15204352
#define WS_WBASE    33554432     // persistent weights above Db

extern "C" void kernel_launch(void* const* d_in, const int* in_sizes, int n_in,
                              void* d_out, int out_size, void* d_ws, size_t ws_size,
                              hipStream_t stream)
{
    const float* x         = (const float*)d_in[0];
    const float* patch_w   = (const float*)d_in[1];
    const float* patch_b   = (const float*)d_in[2];
    const float* in_proj_w = (const float*)d_in[3];
    const float* conv1d_w  = (const float*)d_in[4];
    const float* conv1d_b  = (const float*)d_in[5];
    const float* x_proj_w  = (const float*)d_in[6];
    const float* dt_proj_w = (const float*)d_in[7];
    const float* dt_proj_b = (const float*)d_in[8];
    const float* A_log     = (const float*)d_in[9];
    const float* Dp        = (const float*)d_in[10];
    const float* out_proj_w= (const float*)d_in[11];
    const float* deconv_w  = (const float*)d_in[12];
    const float* deconv_b  = (const float*)d_in[13];
    const float* dec_conv_w= (const float*)d_in[14];
    const float* dec_conv_b= (const float*)d_in[15];
    float* out = (float*)d_out;
    float* ws  = (float*)d_ws;

    unsigned short* P16   = (unsigned short*)(ws + WS_DELTA);
    float*          delta = ws + WS_DELTA;
    unsigned short* seq16 = (unsigned short*)(ws + WS_SEQ16);
    unsigned short* xz16  = (unsigned short*)(ws + WS_XZ16);
    unsigned short* u16   = (unsigned short*)(ws + WS_U16);
    unsigned short* y16   = (unsigned short*)(ws + WS_Y16);
    float*          bc    = ws + WS_BC;
    float*          Pc    = ws + WS_PC;
    float*          Hc    = ws + WS_HC;
    float*          h0c   = ws + WS_H0C;
    unsigned short* Db16  = (unsigned short*)(ws);
    unsigned short* seqo_b= (unsigned short*)(ws + WS_WBASE);              // 786432 f
    unsigned short* W2b   = (unsigned short*)(ws + WS_WBASE + 786432);     // 1572864 f
    unsigned short* wconv = (unsigned short*)(ws + WS_WBASE + 2359296);    // 2304 f
    unsigned short* wp16  = (unsigned short*)(ws + WS_WBASE + 2361600);    // 73728 f
    unsigned short* wi16  = (unsigned short*)(ws + WS_WBASE + 2435328);    // 73728 f
    unsigned short* wo16  = (unsigned short*)(ws + WS_WBASE + 2509056);    // 36864 f
    unsigned short* wxd   = (unsigned short*)(ws + WS_WBASE + 2545920);    // 79872 f

    // 1. fused prep: im2col + all weight transforms
    prep_all<<<38964, 256, 0, stream>>>(x, P16, patch_w, wp16, in_proj_w, wi16,
                                        out_proj_w, wo16, deconv_w, W2b,
                                        dec_conv_w, wconv, dt_proj_w, x_proj_w, wxd);
    // 2. patch embedding -> seq16 bf16
    gemm_mfma_flex<<<dim3(2, 64), 256, 0, stream>>>(P16, wp16, seq16, patch_b,
                                                    8192, 192, 768, 1);
    // 3. in_proj -> xz16 bf16
    gemm_mfma_flex<<<dim3(6, 64), 256, 0, stream>>>(seq16, wi16, xz16, nullptr,
                                                    8192, 768, 192, 1);
    // 4. conv1d + silu -> u16
    conv1d_silu<<<12288, 256, 0, stream>>>(xz16, conv1d_w, conv1d_b, u16);
    // 5. combined x_proj+dt_proj -> delta (softplus) + bc
    gemm_xd<<<dim3(4, 64), 256, 0, stream>>>(u16, wxd, delta, bc, dt_proj_b);
    // 6. selective scan (3-pass, 32 chunks of 32)
    ssm_pass1<<<dim3(32, 6, 8), 256, 0, stream>>>(delta, bc, u16, A_log, Pc, Hc);
    ssm_pass2<<<192, 256, 0, stream>>>(Pc, Hc, h0c);
    ssm_pass3<<<dim3(32, 6, 8), 256, 0, stream>>>(delta, bc, u16, xz16, A_log, Dp, h0c, y16);
    // 7. out_proj -> seqo_b bf16
    gemm_mfma_flex<<<dim3(2, 64), 256, 0, stream>>>(y16, wo16, seqo_b, nullptr,
                                                    8192, 192, 384, 1);
    // 8. decoder: 2 groups x (4-batch MFMA GEMM -> 4-batch MFMA conv+sigmoid)
    for (int g = 0; g < 2; ++g) {
        gemm_mfma_relu_bf16<<<dim3(128, 8, 4), 256, 0, stream>>>(
            seqo_b, W2b, Db16, deconv_b, g * 4);
        decconv_mfma<<<dim3(1024, 4), 256, 0, stream>>>(Db16, wconv, dec_conv_b, out, g * 4);
    }
}

// Round 12
// 512.371 us; speedup vs baseline: 1.0500x; 1.0408x over previous
//
#include <hip/hip_runtime.h>
#include <math.h>

// ---------------------------------------------------------------------------
// VisionMambaDenoiser. Round 12: decoder GEMM staging via
// __builtin_amdgcn_global_load_lds width=16 (m97 ladder step: kills the VGPR
// round-trip + staging VALU; LDS tiles unpadded stride-32 for lane-contiguous
// DMA). R11 falsified drain theory (epilogue fix neutral); R10 falsified
// conflict theory. Remaining suspect: load-latency exposure in the 6-iter
// single-buffered K-loop. Everything else identical to R11 (passing).
// ---------------------------------------------------------------------------

typedef short bf16x8 __attribute__((ext_vector_type(8)));
typedef float f32x4 __attribute__((ext_vector_type(4)));

typedef __attribute__((address_space(3))) unsigned int lds_u32_t;
typedef __attribute__((address_space(1))) const unsigned int glb_u32_t;

__device__ __forceinline__ void dma16(const unsigned short* g, unsigned short* l) {
    // 16B per lane, LDS dest = wave-uniform base + lane*16 (lane-contiguous)
    __builtin_amdgcn_global_load_lds((glb_u32_t*)g, (lds_u32_t*)l, 16, 0, 0);
}

__device__ inline unsigned short f2bf(float f) {
    unsigned int u = __float_as_uint(f);
    unsigned int r = (u + 0x7fff + ((u >> 16) & 1)) >> 16;   // RNE
    return (unsigned short)r;
}
__device__ inline float bf2f(unsigned short s) {
    return __uint_as_float(((unsigned int)s) << 16);
}

// ---------------- flexible bf16 MFMA GEMM: C = A @ W^T (+bias) --------------
__global__ __launch_bounds__(256) void gemm_mfma_flex(
    const unsigned short* __restrict__ A, const unsigned short* __restrict__ W,
    void* __restrict__ Cout, const float* __restrict__ bias,
    int M, int N, int K, int out_bf16)
{
    __shared__ unsigned short As[128][40];
    __shared__ unsigned short Bs[128][40];
    const int tid = threadIdx.x;
    const int wave = tid >> 6, lane = tid & 63;
    const int wm = (wave & 1) * 64, wn = (wave >> 1) * 64;
    const int m0 = blockIdx.y * 128, n0 = blockIdx.x * 128;
    const int quad = lane >> 4, lr = lane & 15;
    const uint4 z4 = {0, 0, 0, 0};

    f32x4 acc[4][4];
    #pragma unroll
    for (int i = 0; i < 4; ++i)
        #pragma unroll
        for (int j = 0; j < 4; ++j)
            acc[i][j] = (f32x4){0.f, 0.f, 0.f, 0.f};

    const int r = tid >> 2, kq = tid & 3;
    for (int k0 = 0; k0 < K; k0 += 32) {
        #pragma unroll
        for (int half = 0; half < 2; ++half) {
            int rr = r + half * 64;
            *(uint4*)(&As[rr][kq * 8]) =
                *(const uint4*)(A + (size_t)(m0 + rr) * K + k0 + kq * 8);
            uint4 bv = z4;
            if (n0 + rr < N)
                bv = *(const uint4*)(W + (size_t)(n0 + rr) * K + k0 + kq * 8);
            *(uint4*)(&Bs[rr][kq * 8]) = bv;
        }
        __syncthreads();
        bf16x8 af[4], bfr[4];
        #pragma unroll
        for (int i = 0; i < 4; ++i) af[i] = *(const bf16x8*)(&As[wm + i * 16 + lr][quad * 8]);
        #pragma unroll
        for (int j = 0; j < 4; ++j) bfr[j] = *(const bf16x8*)(&Bs[wn + j * 16 + lr][quad * 8]);
        #pragma unroll
        for (int i = 0; i < 4; ++i)
            #pragma unroll
            for (int j = 0; j < 4; ++j)
                acc[i][j] = __builtin_amdgcn_mfma_f32_16x16x32_bf16(af[i], bfr[j], acc[i][j], 0, 0, 0);
        __syncthreads();
    }

    #pragma unroll
    for (int i = 0; i < 4; ++i) {
        int gm = m0 + wm + i * 16 + quad * 4;
        #pragma unroll
        for (int j = 0; j < 4; ++j) {
            int gn = n0 + wn + j * 16 + lr;
            if (gn >= N) continue;
            float bv = bias ? bias[gn] : 0.f;
            #pragma unroll
            for (int rr = 0; rr < 4; ++rr) {
                float v = acc[i][j][rr] + bv;
                if (out_bf16) ((unsigned short*)Cout)[(size_t)(gm + rr) * N + gn] = f2bf(v);
                else          ((float*)Cout)[(size_t)(gm + rr) * N + gn] = v;
            }
        }
    }
}

// ---------------- combined x_proj+dt_proj GEMM (N=416, K=384) ---------------
__global__ __launch_bounds__(256) void gemm_xd(
    const unsigned short* __restrict__ A, const unsigned short* __restrict__ W,
    float* __restrict__ delta, float* __restrict__ bc,
    const float* __restrict__ dtb)
{
    __shared__ unsigned short As[128][40];
    __shared__ unsigned short Bs[128][40];
    const int N = 416, K = 384;
    const int tid = threadIdx.x;
    const int wave = tid >> 6, lane = tid & 63;
    const int wm = (wave & 1) * 64, wn = (wave >> 1) * 64;
    const int m0 = blockIdx.y * 128, n0 = blockIdx.x * 128;
    const int quad = lane >> 4, lr = lane & 15;
    const uint4 z4 = {0, 0, 0, 0};

    f32x4 acc[4][4];
    #pragma unroll
    for (int i = 0; i < 4; ++i)
        #pragma unroll
        for (int j = 0; j < 4; ++j)
            acc[i][j] = (f32x4){0.f, 0.f, 0.f, 0.f};

    const int r = tid >> 2, kq = tid & 3;
    for (int k0 = 0; k0 < K; k0 += 32) {
        #pragma unroll
        for (int half = 0; half < 2; ++half) {
            int rr = r + half * 64;
            *(uint4*)(&As[rr][kq * 8]) =
                *(const uint4*)(A + (size_t)(m0 + rr) * K + k0 + kq * 8);
            uint4 bv = z4;
            if (n0 + rr < N)
                bv = *(const uint4*)(W + (size_t)(n0 + rr) * K + k0 + kq * 8);
            *(uint4*)(&Bs[rr][kq * 8]) = bv;
        }
        __syncthreads();
        bf16x8 af[4], bfr[4];
        #pragma unroll
        for (int i = 0; i < 4; ++i) af[i] = *(const bf16x8*)(&As[wm + i * 16 + lr][quad * 8]);
        #pragma unroll
        for (int j = 0; j < 4; ++j) bfr[j] = *(const bf16x8*)(&Bs[wn + j * 16 + lr][quad * 8]);
        #pragma unroll
        for (int i = 0; i < 4; ++i)
            #pragma unroll
            for (int j = 0; j < 4; ++j)
                acc[i][j] = __builtin_amdgcn_mfma_f32_16x16x32_bf16(af[i], bfr[j], acc[i][j], 0, 0, 0);
        __syncthreads();
    }

    #pragma unroll
    for (int i = 0; i < 4; ++i) {
        int gm = m0 + wm + i * 16 + quad * 4;
        #pragma unroll
        for (int j = 0; j < 4; ++j) {
            int gn = n0 + wn + j * 16 + lr;
            if (gn >= N) continue;
            #pragma unroll
            for (int rr = 0; rr < 4; ++rr) {
                float v = acc[i][j][rr];
                if (gn < 384) {
                    v += dtb[gn];
                    v = (v > 20.f) ? v : log1pf(__expf(v));
                    delta[(size_t)(gm + rr) * 384 + gn] = v;
                } else {
                    bc[(size_t)(gm + rr) * 32 + gn - 384] = v;
                }
            }
        }
    }
}

// ---------------- decoder MFMA GEMM (4 batches): Db=bf16(relu(A@W^T+b)) -----
// Staging via global_load_lds width=16 into unpadded stride-32 tiles
// (lane-contiguous DMA). Single-pass no-drain epilogue (R11).
__global__ __launch_bounds__(256) void gemm_mfma_relu_bf16(
    const unsigned short* __restrict__ A0, const unsigned short* __restrict__ W,
    unsigned short* __restrict__ C0, const float* __restrict__ bias, int base_b)
{
    __shared__ unsigned short smem[17408];   // As [0,8192) | Bs [8192,16384) | Ct (128x136)
    const int N = 16384, K = 192;
    const int tid = threadIdx.x;
    const int wave = tid >> 6, lane = tid & 63;
    const int wm = (wave & 1) * 64, wn = (wave >> 1) * 64;
    const int m0 = blockIdx.y * 128, n0 = blockIdx.x * 128;
    const int z = blockIdx.z;
    const unsigned short* A = A0 + (size_t)(base_b + z) * 1024 * 192;
    unsigned short* C = C0 + (size_t)z * 16777216;
    const int quad = lane >> 4, lr = lane & 15;

    f32x4 acc[4][4];
    #pragma unroll
    for (int i = 0; i < 4; ++i)
        #pragma unroll
        for (int j = 0; j < 4; ++j)
            acc[i][j] = (f32x4){0.f, 0.f, 0.f, 0.f};

    for (int k0 = 0; k0 < K; k0 += 32) {
        // DMA staging: tile = 512 chunks of 16B; chunk c -> row=c>>2, kq=c&3,
        // LDS byte addr = c*16 (row-major stride 32 ushorts). Wave w covers
        // chunks [w*128, w*128+128) in 2 lane-contiguous issues per operand.
        #pragma unroll
        for (int half = 0; half < 2; ++half) {
            int c = wave * 128 + half * 64 + lane;
            int row = c >> 2, kq = c & 3;
            dma16(A + (size_t)(m0 + row) * K + k0 + kq * 8, smem + c * 8);
            dma16(W + (size_t)(n0 + row) * K + k0 + kq * 8, smem + 8192 + c * 8);
        }
        __syncthreads();                     // compiler inserts vmcnt drain
        bf16x8 af[4], bfr[4];
        #pragma unroll
        for (int i = 0; i < 4; ++i)
            af[i] = *(const bf16x8*)(&smem[(wm + i * 16 + lr) * 32 + quad * 8]);
        #pragma unroll
        for (int j = 0; j < 4; ++j)
            bfr[j] = *(const bf16x8*)(&smem[8192 + (wn + j * 16 + lr) * 32 + quad * 8]);
        #pragma unroll
        for (int i = 0; i < 4; ++i)
            #pragma unroll
            for (int j = 0; j < 4; ++j)
                acc[i][j] = __builtin_amdgcn_mfma_f32_16x16x32_bf16(af[i], bfr[j], acc[i][j], 0, 0, 0);
        __syncthreads();
    }

    // single-pass epilogue: all waves write Ct, one barrier, stores, no drain
    unsigned short* Ct = smem;               // 128*136 = 17408 ushorts
    #pragma unroll
    for (int i = 0; i < 4; ++i) {
        int lrow = wm + i * 16 + quad * 4;
        #pragma unroll
        for (int j = 0; j < 4; ++j) {
            int lcol = wn + j * 16 + lr;
            float bv = bias[(n0 + lcol) & 63];
            #pragma unroll
            for (int rr = 0; rr < 4; ++rr) {
                float v = fmaxf(acc[i][j][rr] + bv, 0.f);
                Ct[(lrow + rr) * 136 + lcol] = f2bf(v);
            }
        }
    }
    __syncthreads();
    #pragma unroll
    for (int p = 0; p < 8; ++p) {
        int idx = p * 256 + tid;             // 0..2047
        int row = idx >> 4, cg = idx & 15;
        *(uint4*)(C + (size_t)(m0 + row) * N + n0 + cg * 8) =
            *(const uint4*)(&Ct[row * 136 + cg * 8]);
    }
    // no trailing barrier: stores drain while other blocks compute
}

// ---------------- fused prep: im2col + all weight transforms ----------------
__global__ __launch_bounds__(256) void prep_all(
    const float* __restrict__ x, unsigned short* __restrict__ P,
    const float* __restrict__ patch_w, unsigned short* __restrict__ wp,
    const float* __restrict__ in_proj_w, unsigned short* __restrict__ wi,
    const float* __restrict__ out_proj_w, unsigned short* __restrict__ wo,
    const float* __restrict__ deconv_w, unsigned short* __restrict__ W2,
    const float* __restrict__ dec_conv_w, unsigned short* __restrict__ wconv,
    const float* __restrict__ dtw, const float* __restrict__ xpw,
    unsigned short* __restrict__ wxd)
{
    int i = blockIdx.x * 256 + threadIdx.x;     // 9974784 total
    if (i < 6291456) {
        int col = i % 768, row = i / 768;
        int b = row >> 10, l = row & 1023;
        int h = l >> 5, w = l & 31;
        int c = col >> 8, p = (col >> 4) & 15, q = col & 15;
        P[i] = f2bf(x[((size_t)(b * 3 + c) * 512 + (h * 16 + p)) * 512 + (w * 16 + q)]);
        return;
    }
    i -= 6291456;
    if (i < 147456) { wp[i] = f2bf(patch_w[i]); return; }
    i -= 147456;
    if (i < 147456) { wi[i] = f2bf(in_proj_w[i]); return; }
    i -= 147456;
    if (i < 73728) { wo[i] = f2bf(out_proj_w[i]); return; }
    i -= 73728;
    if (i < 3145728) {                          // deconv_w -> W2[(p16+q)*64+k][c]
        int c = i % 192, np = i / 192;
        int k = np & 63, pq = np >> 6;
        W2[i] = f2bf(deconv_w[(size_t)c * 16384 + k * 256 + pq]);
        return;
    }
    i -= 3145728;
    if (i < 9216) {                             // dec_conv_w -> wconv[tap][m16][ch]
        int ch = i & 63, m = (i >> 6) & 15, tap = i >> 10;
        int dy = tap / 3, dx = tap % 3;
        float v = (m < 3) ? dec_conv_w[((m * 64 + ch) * 3 + dy) * 3 + dx] : 0.f;
        wconv[i] = f2bf(v);
        return;
    }
    i -= 9216;
    {                                           // wxd (416 x 384)
        int col = i % 384, row = i / 384;
        float v;
        if (row < 384) {
            v = 0.f;
            #pragma unroll
            for (int j = 0; j < 12; ++j)
                v = fmaf(dtw[row * 12 + j], xpw[j * 384 + col], v);
        } else {
            v = xpw[(row - 384 + 12) * 384 + col];
        }
        wxd[i] = f2bf(v);
    }
}

// ---------------- depthwise causal conv1d + silu (bf16 in/out) --------------
__global__ __launch_bounds__(256) void conv1d_silu(const unsigned short* __restrict__ xz,
                                                   const float* __restrict__ cw,
                                                   const float* __restrict__ cb,
                                                   unsigned short* __restrict__ u16)
{
    int idx = blockIdx.x * 256 + threadIdx.x;   // 8192*384
    int d = idx % 384;
    int row = idx / 384;
    int l = row & 1023;
    float acc = cb[d];
    #pragma unroll
    for (int j = 0; j < 4; ++j) {
        int ll = l - 3 + j;
        if (ll >= 0) acc += bf2f(xz[(size_t)(row - 3 + j) * 768 + d]) * cw[d * 4 + j];
    }
    float s = acc / (1.f + __expf(-acc));
    u16[idx] = f2bf(s);
}

// ---------------- selective scan, 3-pass: 32 chunks of 32 -------------------
__global__ __launch_bounds__(256) void ssm_pass1(const float* __restrict__ delta,
                                                 const float* __restrict__ bc,
                                                 const unsigned short* __restrict__ u,
                                                 const float* __restrict__ A_log,
                                                 float* __restrict__ Pc,
                                                 float* __restrict__ Hc)
{
    const int tid = threadIdx.x;
    const int n4 = tid & 3, dloc = tid >> 2;
    const int c = blockIdx.x, dg = blockIdx.y, b = blockIdx.z;
    const int d = dg * 64 + dloc;
    const int blk = (b * 6 + dg) * 32 + c;
    f32x4 A4 = *(const f32x4*)(A_log + d * 16 + n4 * 4);
    float Aa[4];
    #pragma unroll
    for (int j = 0; j < 4; ++j) Aa[j] = -__expf(A4[j]);
    const float* dp = delta + (size_t)(b * 1024) * 384 + d;
    const unsigned short* up = u + (size_t)(b * 1024) * 384 + d;
    const float* bp = bc    + (size_t)(b * 1024) * 32;
    float P[4] = {1.f, 1.f, 1.f, 1.f}, H[4] = {0.f, 0.f, 0.f, 0.f};
    const int l0 = c * 32;
    for (int l = l0; l < l0 + 32; ++l) {
        float dlv = dp[(size_t)l * 384];
        float ulv = bf2f(up[(size_t)l * 384]);
        f32x4 B4 = *(const f32x4*)(bp + (size_t)l * 32 + n4 * 4);
        float du = dlv * ulv;
        #pragma unroll
        for (int j = 0; j < 4; ++j) {
            float a = __expf(dlv * Aa[j]);
            P[j] *= a;
            H[j] = fmaf(a, H[j], du * B4[j]);
        }
    }
    size_t o = ((size_t)blk * 256 + tid) * 4;
    *(f32x4*)(Pc + o) = (f32x4){P[0], P[1], P[2], P[3]};
    *(f32x4*)(Hc + o) = (f32x4){H[0], H[1], H[2], H[3]};
}

__global__ __launch_bounds__(256) void ssm_pass2(const float* __restrict__ Pc,
                                                 const float* __restrict__ Hc,
                                                 float* __restrict__ h0c)
{
    int t = blockIdx.x * 256 + threadIdx.x;    // 49152
    int grp = t >> 10, dn = t & 1023;
    float h = 0.f;
    #pragma unroll
    for (int c = 0; c < 32; ++c) {
        size_t idx = ((size_t)(grp * 32 + c)) * 1024 + dn;
        h0c[idx] = h;
        h = fmaf(Pc[idx], h, Hc[idx]);
    }
}

__global__ __launch_bounds__(256) void ssm_pass3(const float* __restrict__ delta,
                                                 const float* __restrict__ bc,
                                                 const unsigned short* __restrict__ u,
                                                 const unsigned short* __restrict__ xz,
                                                 const float* __restrict__ A_log,
                                                 const float* __restrict__ Dp,
                                                 const float* __restrict__ h0c,
                                                 unsigned short* __restrict__ y16)
{
    const int tid = threadIdx.x;
    const int n4 = tid & 3, dloc = tid >> 2;
    const int c = blockIdx.x, dg = blockIdx.y, b = blockIdx.z;
    const int d = dg * 64 + dloc;
    const int blk = (b * 6 + dg) * 32 + c;
    f32x4 A4 = *(const f32x4*)(A_log + d * 16 + n4 * 4);
    float Aa[4];
    #pragma unroll
    for (int j = 0; j < 4; ++j) Aa[j] = -__expf(A4[j]);
    float Dv = Dp[d];
    const float* dp = delta + (size_t)(b * 1024) * 384 + d;
    const unsigned short* up = u + (size_t)(b * 1024) * 384 + d;
    const float* bp = bc    + (size_t)(b * 1024) * 32;
    const unsigned short* zp = xz + (size_t)(b * 1024) * 768 + 384 + d;
    unsigned short* yp = y16 + (size_t)(b * 1024) * 384 + d;
    f32x4 h4 = *(const f32x4*)(h0c + ((size_t)blk * 256 + tid) * 4);
    float H[4] = {h4[0], h4[1], h4[2], h4[3]};
    const int l0 = c * 32;
    for (int l = l0; l < l0 + 32; ++l) {
        float dlv = dp[(size_t)l * 384];
        float ulv = bf2f(up[(size_t)l * 384]);
        f32x4 B4 = *(const f32x4*)(bp + (size_t)l * 32 + n4 * 4);
        f32x4 C4 = *(const f32x4*)(bp + (size_t)l * 32 + 16 + n4 * 4);
        float du = dlv * ulv;
        float part = 0.f;
        #pragma unroll
        for (int j = 0; j < 4; ++j) {
            float a = __expf(dlv * Aa[j]);
            H[j] = fmaf(a, H[j], du * B4[j]);
            part = fmaf(H[j], C4[j], part);
        }
        part += __shfl_xor(part, 1, 4);
        part += __shfl_xor(part, 2, 4);
        if (n4 == 0) {
            float z = bf2f(zp[(size_t)l * 768]);
            float sz = z / (1.f + __expf(-z));
            yp[(size_t)l * 384] = f2bf((part + ulv * Dv) * sz);
        }
    }
}

// ---------------- MFMA 3x3 conv (64->3) + bias + sigmoid, 4 batches ---------
__global__ __launch_bounds__(256) void decconv_mfma(
    const unsigned short* __restrict__ Db, const unsigned short* __restrict__ wconv,
    const float* __restrict__ dcb, float* __restrict__ out, int base_b)
{
    __shared__ unsigned short ds[18 * 18 * 72];
    const int t = threadIdx.x;
    const int pidx = blockIdx.x;
    const int bb = blockIdx.y;
    const int b = base_b + bb;
    const unsigned short* Dbb = Db + (size_t)bb * 16777216;
    const int ph = pidx >> 5, pw = pidx & 31;
    const uint4 z4 = {0, 0, 0, 0};

    const unsigned short* base = Dbb + ((size_t)pidx << 14);
    #pragma unroll
    for (int s = 0; s < 8; ++s) {
        int f = s * 256 + t;
        int k8 = f & 7, pq = f >> 3;
        *(uint4*)&ds[(((pq >> 4) + 1) * 18 + (pq & 15) + 1) * 72 + k8 * 8] =
            *(const uint4*)(base + pq * 64 + k8 * 8);
    }
    {
        int k8 = t & 7, e = (t >> 3) & 15;
        if (t < 128) {
            uint4 v = z4;
            if (ph > 0) v = *(const uint4*)(Dbb + ((size_t)(pidx - 32) << 14) + (240 + e) * 64 + k8 * 8);
            *(uint4*)&ds[(0 * 18 + e + 1) * 72 + k8 * 8] = v;
        } else {
            uint4 v = z4;
            if (ph < 31) v = *(const uint4*)(Dbb + ((size_t)(pidx + 32) << 14) + e * 64 + k8 * 8);
            *(uint4*)&ds[(17 * 18 + e + 1) * 72 + k8 * 8] = v;
        }
        if (t < 128) {
            uint4 v = z4;
            if (pw > 0) v = *(const uint4*)(Dbb + ((size_t)(pidx - 1) << 14) + (e * 16 + 15) * 64 + k8 * 8);
            *(uint4*)&ds[((e + 1) * 18 + 0) * 72 + k8 * 8] = v;
        } else {
            uint4 v = z4;
            if (pw < 31) v = *(const uint4*)(Dbb + ((size_t)(pidx + 1) << 14) + (e * 16) * 64 + k8 * 8);
            *(uint4*)&ds[((e + 1) * 18 + 17) * 72 + k8 * 8] = v;
        }
        if (t < 32) {
            int c = t >> 3;
            int dh = (c >> 1) * 2 - 1, dw = (c & 1) * 2 - 1;
            int nh = ph + dh, nw = pw + dw;
            int sp = dh < 0 ? 15 : 0, sq = dw < 0 ? 15 : 0;
            uint4 v = z4;
            if (nh >= 0 && nh < 32 && nw >= 0 && nw < 32)
                v = *(const uint4*)(Dbb + ((size_t)(nh * 32 + nw) << 14) + (sp * 16 + sq) * 64 + k8 * 8);
            int dy = dh < 0 ? 0 : 17, dx = dw < 0 ? 0 : 17;
            *(uint4*)&ds[(dy * 18 + dx) * 72 + k8 * 8] = v;
        }
    }
    __syncthreads();

    const int wave = t >> 6, lane = t & 63;
    const int quad = lane >> 4, lr = lane & 15;
    f32x4 acc[4];
    #pragma unroll
    for (int i = 0; i < 4; ++i) acc[i] = (f32x4){0.f, 0.f, 0.f, 0.f};

    #pragma unroll
    for (int tap = 0; tap < 9; ++tap) {
        const int dy = tap / 3, dx = tap % 3;
        bf16x8 a0 = *(const bf16x8*)(wconv + (tap * 16 + lr) * 64 + quad * 8);
        bf16x8 a1 = *(const bf16x8*)(wconv + (tap * 16 + lr) * 64 + 32 + quad * 8);
        #pragma unroll
        for (int i = 0; i < 4; ++i) {
            int p = wave * 4 + i;
            const unsigned short* cell = &ds[((p + dy) * 18 + lr + dx) * 72];
            bf16x8 b0 = *(const bf16x8*)(cell + quad * 8);
            bf16x8 b1 = *(const bf16x8*)(cell + 32 + quad * 8);
            acc[i] = __builtin_amdgcn_mfma_f32_16x16x32_bf16(a0, b0, acc[i], 0, 0, 0);
            acc[i] = __builtin_amdgcn_mfma_f32_16x16x32_bf16(a1, b1, acc[i], 0, 0, 0);
        }
    }

    if (quad == 0) {
        float b0 = dcb[0], b1 = dcb[1], b2 = dcb[2];
        #pragma unroll
        for (int i = 0; i < 4; ++i) {
            int Y = ph * 16 + wave * 4 + i, X = pw * 16 + lr;
            size_t o = (size_t)(b * 3) * 262144 + (size_t)Y * 512 + X;
            out[o]          = 1.f / (1.f + __expf(-(acc[i][0] + b0)));
            out[o + 262144] = 1.f / (1.f + __expf(-(acc[i][1] + b1)));
            out[o + 524288] = 1.f / (1.f + __expf(-(acc[i][2] + b2)));
        }
    }
}

// ---------------------------------------------------------------------------
// Workspace layout (float units) — audited sizes:
//   8192x768 bf16 = 3,145,728 f; 8192x384 bf16 = 1,572,864 f;
//   8192x192 bf16 =   786,432 f; 16384x192 bf16 = 1,572,864 f.
// Encoder scratch [0, 15204352). Decoder Db bf16 4-batch = [0, 33554432).
// Persistent weights at 33554432..36180224 < 67108864 (ws = 256 MiB).
// ---------------------------------------------------------------------------
#define WS_DELTA    0            // f32 8192x384 (3145728 f); P16 aliases (dead after step 2)
#define WS_SEQ16    3145728      // bf16 8192x192 (786432 f) -> 3932160, dead after in_proj
#define WS_XZ16     3932160      // bf16 8192x768 (3145728 f) -> 7077888
#define WS_U16      7077888      // bf16 8192x384 (1572864 f) -> 8650752
#define WS_Y16      8650752      // bf16 8192x384 (1572864 f) -> 10223616
#define WS_BC       10223616     // f32 8192x32 (262144 f) -> 10485760
#define WS_PC       10485760     // 1572864 -> 12058624
#define WS_HC       12058624     // 1572864 -> 13631488
#define WS_H0C      13631488     // 1572864 -> 15204352
#define WS_WBASE    33554432     // persistent weights above Db

extern "C" void kernel_launch(void* const* d_in, const int* in_sizes, int n_in,
                              void* d_out, int out_size, void* d_ws, size_t ws_size,
                              hipStream_t stream)
{
    const float* x         = (const float*)d_in[0];
    const float* patch_w   = (const float*)d_in[1];
    const float* patch_b   = (const float*)d_in[2];
    const float* in_proj_w = (const float*)d_in[3];
    const float* conv1d_w  = (const float*)d_in[4];
    const float* conv1d_b  = (const float*)d_in[5];
    const float* x_proj_w  = (const float*)d_in[6];
    const float* dt_proj_w = (const float*)d_in[7];
    const float* dt_proj_b = (const float*)d_in[8];
    const float* A_log     = (const float*)d_in[9];
    const float* Dp        = (const float*)d_in[10];
    const float* out_proj_w= (const float*)d_in[11];
    const float* deconv_w  = (const float*)d_in[12];
    const float* deconv_b  = (const float*)d_in[13];
    const float* dec_conv_w= (const float*)d_in[14];
    const float* dec_conv_b= (const float*)d_in[15];
    float* out = (float*)d_out;
    float* ws  = (float*)d_ws;

    unsigned short* P16   = (unsigned short*)(ws + WS_DELTA);
    float*          delta = ws + WS_DELTA;
    unsigned short* seq16 = (unsigned short*)(ws + WS_SEQ16);
    unsigned short* xz16  = (unsigned short*)(ws + WS_XZ16);
    unsigned short* u16   = (unsigned short*)(ws + WS_U16);
    unsigned short* y16   = (unsigned short*)(ws + WS_Y16);
    float*          bc    = ws + WS_BC;
    float*          Pc    = ws + WS_PC;
    float*          Hc    = ws + WS_HC;
    float*          h0c   = ws + WS_H0C;
    unsigned short* Db16  = (unsigned short*)(ws);
    unsigned short* seqo_b= (unsigned short*)(ws + WS_WBASE);              // 786432 f
    unsigned short* W2b   = (unsigned short*)(ws + WS_WBASE + 786432);     // 1572864 f
    unsigned short* wconv = (unsigned short*)(ws + WS_WBASE + 2359296);    // 2304 f
    unsigned short* wp16  = (unsigned short*)(ws + WS_WBASE + 2361600);    // 73728 f
    unsigned short* wi16  = (unsigned short*)(ws + WS_WBASE + 2435328);    // 73728 f
    unsigned short* wo16  = (unsigned short*)(ws + WS_WBASE + 2509056);    // 36864 f
    unsigned short* wxd   = (unsigned short*)(ws + WS_WBASE + 2545920);    // 79872 f

    // 1. fused prep: im2col + all weight transforms
    prep_all<<<38964, 256, 0, stream>>>(x, P16, patch_w, wp16, in_proj_w, wi16,
                                        out_proj_w, wo16, deconv_w, W2b,
                                        dec_conv_w, wconv, dt_proj_w, x_proj_w, wxd);
    // 2. patch embedding -> seq16 bf16
    gemm_mfma_flex<<<dim3(2, 64), 256, 0, stream>>>(P16, wp16, seq16, patch_b,
                                                    8192, 192, 768, 1);
    // 3. in_proj -> xz16 bf16
    gemm_mfma_flex<<<dim3(6, 64), 256, 0, stream>>>(seq16, wi16, xz16, nullptr,
                                                    8192, 768, 192, 1);
    // 4. conv1d + silu -> u16
    conv1d_silu<<<12288, 256, 0, stream>>>(xz16, conv1d_w, conv1d_b, u16);
    // 5. combined x_proj+dt_proj -> delta (softplus) + bc
    gemm_xd<<<dim3(4, 64), 256, 0, stream>>>(u16, wxd, delta, bc, dt_proj_b);
    // 6. selective scan (3-pass, 32 chunks of 32)
    ssm_pass1<<<dim3(32, 6, 8), 256, 0, stream>>>(delta, bc, u16, A_log, Pc, Hc);
    ssm_pass2<<<192, 256, 0, stream>>>(Pc, Hc, h0c);
    ssm_pass3<<<dim3(32, 6, 8), 256, 0, stream>>>(delta, bc, u16, xz16, A_log, Dp, h0c, y16);
    // 7. out_proj -> seqo_b bf16
    gemm_mfma_flex<<<dim3(2, 64), 256, 0, stream>>>(y16, wo16, seqo_b, nullptr,
                                                    8192, 192, 384, 1);
    // 8. decoder: 2 groups x (4-batch MFMA GEMM -> 4-batch MFMA conv+sigmoid)
    for (int g = 0; g < 2; ++g) {
        gemm_mfma_relu_bf16<<<dim3(128, 8, 4), 256, 0, stream>>>(
            seqo_b, W2b, Db16, deconv_b, g * 4);
        decconv_mfma<<<dim3(1024, 4), 256, 0, stream>>>(Db16, wconv, dec_conv_b, out, g * 4);
    }
}